// Round 1
// baseline (34.043 us; speedup 1.0000x reference)
//
#include <hip/hip_runtime.h>

// PolicyNetwork: scores[r,t] = b2 + sum_h W2[h] * relu(rp[r,h] + tp[t,h])
//   rp = robot @ W1[:D] + b1   [512, 512]
//   tp = task  @ W1[D:]        [512, 512]
// R=T=512, D=256, H=512, fp32 throughout.
// d_ws layout: rp at ws[0 .. 512*512), tp at ws[512*512 .. 2*512*512)  (2 MB)

#define R_DIM 512
#define T_DIM 512
#define D_DIM 256
#define H_DIM 512
#define S2 258   // LDS row stride for stage 2 (even for 8B alignment, 2*S2 % 32 == 4 -> 2-way-free banks)

// ---------------- Stage 1: two 512x512x256 fp32 GEMMs ----------------
// z = 0: out = robot @ W1[0:256]  + b1   -> ws[0:]
// z = 1: out = task  @ W1[256:512]       -> ws[512*512:]
// Tile: 64 (m) x 32 (n), K-chunk 32. 256 threads, micro-tile 4x2.
__global__ __launch_bounds__(256) void gemm_parts(
    const float* __restrict__ robot, const float* __restrict__ task,
    const float* __restrict__ W1, const float* __restrict__ b1,
    float* __restrict__ ws)
{
    const int z = blockIdx.z;
    const float* A = z ? task : robot;
    const float* B = W1 + z * (D_DIM * H_DIM);
    float* outp = ws + z * (R_DIM * H_DIM);

    __shared__ float As[32 * 68];  // As[k][m], padded stride 68
    __shared__ float Bs[32 * 34];  // Bs[k][n], padded stride 34

    const int tid = threadIdx.x;
    const int tx = tid & 15;   // n direction
    const int ty = tid >> 4;   // m direction
    const int mtile = blockIdx.y * 64;
    const int ntile = blockIdx.x * 32;

    float acc[4][2] = {};

    for (int kc = 0; kc < D_DIM; kc += 32) {
        // A tile 64(m) x 32(k), transposed into As[k][m]
        #pragma unroll
        for (int i = 0; i < 2; ++i) {
            int idx = tid + 256 * i;      // 0..511 float4s
            int m = idx >> 3;             // 0..63
            int kq = (idx & 7) << 2;      // 0,4,..,28
            float4 v = *(const float4*)&A[(mtile + m) * D_DIM + kc + kq];
            As[(kq + 0) * 68 + m] = v.x;
            As[(kq + 1) * 68 + m] = v.y;
            As[(kq + 2) * 68 + m] = v.z;
            As[(kq + 3) * 68 + m] = v.w;
        }
        // B tile 32(k) x 32(n)
        {
            int k = tid >> 3;             // 0..31
            int nq = (tid & 7) << 2;      // 0,4,..,28
            float4 v = *(const float4*)&B[(kc + k) * H_DIM + ntile + nq];
            *(float2*)&Bs[k * 34 + nq]     = make_float2(v.x, v.y);
            *(float2*)&Bs[k * 34 + nq + 2] = make_float2(v.z, v.w);
        }
        __syncthreads();
        #pragma unroll
        for (int k = 0; k < 32; ++k) {
            float4 a = *(const float4*)&As[k * 68 + 4 * ty];
            float2 b = *(const float2*)&Bs[k * 34 + 2 * tx];
            acc[0][0] += a.x * b.x; acc[0][1] += a.x * b.y;
            acc[1][0] += a.y * b.x; acc[1][1] += a.y * b.y;
            acc[2][0] += a.z * b.x; acc[2][1] += a.z * b.y;
            acc[3][0] += a.w * b.x; acc[3][1] += a.w * b.y;
        }
        __syncthreads();
    }

    const int h = ntile + 2 * tx;
    float bx_ = 0.f, by_ = 0.f;
    if (z == 0) { bx_ = b1[h]; by_ = b1[h + 1]; }
    #pragma unroll
    for (int i = 0; i < 4; ++i) {
        float2 v = make_float2(acc[i][0] + bx_, acc[i][1] + by_);
        *(float2*)&outp[(mtile + 4 * ty + i) * H_DIM + h] = v;
    }
}

// ---------------- Stage 2: scores[r,t] = b2 + sum_h W2[h]*relu(rp[r,h]+tp[t,h]) --------
// 32x32 output tile per block, 256 threads, 2x2 micro-tile, H in 2 chunks of 256 in LDS.
__global__ __launch_bounds__(256) void score_kernel(
    const float* __restrict__ ws, const float* __restrict__ W2,
    const float* __restrict__ b2, float* __restrict__ out)
{
    const float* rp = ws;
    const float* tp = ws + R_DIM * H_DIM;

    __shared__ float rs[32 * S2];
    __shared__ float ts[32 * S2];

    const int tid = threadIdx.x;
    const int tx = tid & 15;   // t direction
    const int ty = tid >> 4;   // r direction
    const int rbase = blockIdx.y * 32;
    const int tbase = blockIdx.x * 32;

    float acc00 = 0.f, acc01 = 0.f, acc10 = 0.f, acc11 = 0.f;

    for (int hc = 0; hc < H_DIM; hc += 256) {
        if (hc) __syncthreads();
        // Load 32 rows x 256 cols of rp and tp into LDS (stride S2=258).
        #pragma unroll
        for (int i = 0; i < 8; ++i) {
            int idx = tid + 256 * i;      // 0..2047 float4s
            int r = idx >> 6;             // 0..31
            int q = (idx & 63) << 2;      // 0..252
            float4 v = *(const float4*)&rp[(rbase + r) * H_DIM + hc + q];
            *(float2*)&rs[r * S2 + q]     = make_float2(v.x, v.y);
            *(float2*)&rs[r * S2 + q + 2] = make_float2(v.z, v.w);
            float4 u = *(const float4*)&tp[(tbase + r) * H_DIM + hc + q];
            *(float2*)&ts[r * S2 + q]     = make_float2(u.x, u.y);
            *(float2*)&ts[r * S2 + q + 2] = make_float2(u.z, u.w);
        }
        __syncthreads();

        const int r0 = 2 * ty;
        const int t0 = 2 * tx;
        #pragma unroll 8
        for (int h = 0; h < 256; h += 2) {
            float2 w  = *(const float2*)&W2[hc + h];   // wave-uniform -> s_load
            float2 a0 = *(const float2*)&rs[r0 * S2 + h];
            float2 a1 = *(const float2*)&rs[(r0 + 1) * S2 + h];
            float2 c0 = *(const float2*)&ts[t0 * S2 + h];
            float2 c1 = *(const float2*)&ts[(t0 + 1) * S2 + h];
            acc00 += w.x * fmaxf(a0.x + c0.x, 0.f) + w.y * fmaxf(a0.y + c0.y, 0.f);
            acc01 += w.x * fmaxf(a0.x + c1.x, 0.f) + w.y * fmaxf(a0.y + c1.y, 0.f);
            acc10 += w.x * fmaxf(a1.x + c0.x, 0.f) + w.y * fmaxf(a1.y + c0.y, 0.f);
            acc11 += w.x * fmaxf(a1.x + c1.x, 0.f) + w.y * fmaxf(a1.y + c1.y, 0.f);
        }
    }

    const float b2v = b2[0];
    const int r = rbase + 2 * ty;
    const int t = tbase + 2 * tx;
    *(float2*)&out[r * T_DIM + t]       = make_float2(acc00 + b2v, acc01 + b2v);
    *(float2*)&out[(r + 1) * T_DIM + t] = make_float2(acc10 + b2v, acc11 + b2v);
}

extern "C" void kernel_launch(void* const* d_in, const int* in_sizes, int n_in,
                              void* d_out, int out_size, void* d_ws, size_t ws_size,
                              hipStream_t stream) {
    const float* robot = (const float*)d_in[0];
    const float* task  = (const float*)d_in[1];
    const float* W1    = (const float*)d_in[2];
    const float* b1    = (const float*)d_in[3];
    const float* W2    = (const float*)d_in[4];
    const float* b2    = (const float*)d_in[5];
    float* out = (float*)d_out;
    float* ws  = (float*)d_ws;   // needs 2 MB: rp[512*512] + tp[512*512]

    dim3 g1(H_DIM / 32, R_DIM / 64, 2);   // (16, 8, 2)
    gemm_parts<<<g1, dim3(256), 0, stream>>>(robot, task, W1, b1, ws);

    dim3 g2(T_DIM / 32, R_DIM / 32);      // (16, 16)
    score_kernel<<<g2, dim3(256), 0, stream>>>(ws, W2, b2, out);
}

// Round 2
// 31.076 us; speedup vs baseline: 1.0955x; 1.0955x over previous
//
#include <hip/hip_runtime.h>

// scores[r,t] = b2 + sum_h W2[h] * relu(rp[r,h] + tp[t,h])
//   rp = robot @ W1[:256] + b1   [512, 512]   -> ws[0:]
//   tp = task  @ W1[256:]        [512, 512]   -> ws[262144:]
// R=T=512, D=256, H=512, fp32.

#define D_DIM 256
#define H_DIM 512
#define RT    512
#define SA    262   // As stride (dwords): 4*SA%32==24 -> <=2-way banks on A reads; rows 8B-aligned
#define SB    36    // Bs stride: rows 16B-aligned (144 B)
#define SS    260   // stage-2 LDS stride: rows 16B-aligned (1040 B)

// ---------------- Stage 1: two 512x512x256 fp32 GEMMs ----------------
// Grid (16,16,2), 256 thr. Tile 32x32, full K=256 staged in LDS once.
// 4 waves split K (64 each), micro 4x4 per lane, LDS cross-wave reduce.
__global__ __launch_bounds__(256) void gemm32(
    const float* __restrict__ robot, const float* __restrict__ task,
    const float* __restrict__ W1, const float* __restrict__ b1,
    float* __restrict__ ws)
{
    __shared__ float smem[32 * SA + 256 * SB];   // 70.4 KB -> 2 blocks/CU
    float* As = smem;              // As[m][k], m=0..31, k=0..255
    float* Bs = smem + 32 * SA;    // Bs[k][n], k=0..255, n=0..31

    const int z = blockIdx.z;
    const float* A = z ? task : robot;
    const int tid = threadIdx.x;
    const int mtile = blockIdx.y * 32;
    const int ntile = blockIdx.x * 32;

    // Stage A tile [32 m][256 k] (direct) and B tile [256 k][32 n] (direct).
    #pragma unroll
    for (int i = 0; i < 8; ++i) {
        int idx = tid + 256 * i;            // 0..2047
        {   // A: m = idx>>6, 4k-chunk = (idx&63)*4
            int m = idx >> 6, q = (idx & 63) << 2;
            float4 v = *(const float4*)&A[(mtile + m) * D_DIM + q];
            *(float2*)&As[m * SA + q]     = make_float2(v.x, v.y);   // SA rows are 8B-aligned
            *(float2*)&As[m * SA + q + 2] = make_float2(v.z, v.w);
        }
        {   // B: k = idx>>3, 4n-chunk = (idx&7)*4
            int k = idx >> 3, n0 = (idx & 7) << 2;
            float4 v = *(const float4*)&W1[(z * D_DIM + k) * H_DIM + ntile + n0];
            *(float4*)&Bs[k * SB + n0] = v;
        }
    }
    __syncthreads();

    const int wave = tid >> 6;
    const int lane = tid & 63;
    const int tx = lane & 7;      // n: 8 x 4
    const int ty = lane >> 3;     // m: 8 x 4
    const int kbeg = wave * 64, kend = kbeg + 64;

    float4 acc0 = {0,0,0,0}, acc1 = {0,0,0,0}, acc2 = {0,0,0,0}, acc3 = {0,0,0,0};
    const float* a0p = &As[(4 * ty + 0) * SA];
    const float* a1p = &As[(4 * ty + 1) * SA];
    const float* a2p = &As[(4 * ty + 2) * SA];
    const float* a3p = &As[(4 * ty + 3) * SA];

    #pragma unroll 4
    for (int k = kbeg; k < kend; ++k) {
        float4 b = *(const float4*)&Bs[k * SB + 4 * tx];
        float a0 = a0p[k], a1 = a1p[k], a2 = a2p[k], a3 = a3p[k];
        acc0.x += a0 * b.x; acc0.y += a0 * b.y; acc0.z += a0 * b.z; acc0.w += a0 * b.w;
        acc1.x += a1 * b.x; acc1.y += a1 * b.y; acc1.z += a1 * b.z; acc1.w += a1 * b.w;
        acc2.x += a2 * b.x; acc2.y += a2 * b.y; acc2.z += a2 * b.z; acc2.w += a2 * b.w;
        acc3.x += a3 * b.x; acc3.y += a3 * b.y; acc3.z += a3 * b.z; acc3.w += a3 * b.w;
    }

    // Cross-wave K-reduction through LDS (stride 17 -> conflict-free b32).
    __syncthreads();                 // everyone done reading As/Bs
    float* red = smem;               // 3 * 1088 floats = 13 KB, reuses As
    if (wave > 0) {
        float* p = &red[(wave - 1) * 1088 + lane * 17];
        p[0]=acc0.x; p[1]=acc0.y; p[2]=acc0.z; p[3]=acc0.w;
        p[4]=acc1.x; p[5]=acc1.y; p[6]=acc1.z; p[7]=acc1.w;
        p[8]=acc2.x; p[9]=acc2.y; p[10]=acc2.z; p[11]=acc2.w;
        p[12]=acc3.x; p[13]=acc3.y; p[14]=acc3.z; p[15]=acc3.w;
    }
    __syncthreads();
    if (wave == 0) {
        #pragma unroll
        for (int w = 0; w < 3; ++w) {
            const float* p = &red[w * 1088 + lane * 17];
            acc0.x+=p[0]; acc0.y+=p[1]; acc0.z+=p[2]; acc0.w+=p[3];
            acc1.x+=p[4]; acc1.y+=p[5]; acc1.z+=p[6]; acc1.w+=p[7];
            acc2.x+=p[8]; acc2.y+=p[9]; acc2.z+=p[10]; acc2.w+=p[11];
            acc3.x+=p[12]; acc3.y+=p[13]; acc3.z+=p[14]; acc3.w+=p[15];
        }
        float4 bv = make_float4(0.f, 0.f, 0.f, 0.f);
        if (z == 0) bv = *(const float4*)&b1[ntile + 4 * tx];
        float* op = ws + z * (RT * H_DIM);
        const int col = ntile + 4 * tx;
        *(float4*)&op[(mtile + 4*ty + 0) * H_DIM + col] = make_float4(acc0.x+bv.x, acc0.y+bv.y, acc0.z+bv.z, acc0.w+bv.w);
        *(float4*)&op[(mtile + 4*ty + 1) * H_DIM + col] = make_float4(acc1.x+bv.x, acc1.y+bv.y, acc1.z+bv.z, acc1.w+bv.w);
        *(float4*)&op[(mtile + 4*ty + 2) * H_DIM + col] = make_float4(acc2.x+bv.x, acc2.y+bv.y, acc2.z+bv.z, acc2.w+bv.w);
        *(float4*)&op[(mtile + 4*ty + 3) * H_DIM + col] = make_float4(acc3.x+bv.x, acc3.y+bv.y, acc3.z+bv.z, acc3.w+bv.w);
    }
}

// ---------------- Stage 2: scores = b2 + sum_h W2[h]*relu(rp+tp) ----------------
// Grid (16,16), 256 thr, 32x32 tile, 2x2 micro, H in 2 chunks of 256.
// b128 reads over 4 h; rs reads broadcast (addr by ty only); ts XOR-swizzled.
__global__ __launch_bounds__(256) void score32(
    const float* __restrict__ ws, const float* __restrict__ W2,
    const float* __restrict__ b2, float* __restrict__ out)
{
    const float* rp = ws;
    const float* tp = ws + RT * H_DIM;

    __shared__ float rs[32 * SS];
    __shared__ float ts[32 * SS];

    const int tid = threadIdx.x;
    const int tx = tid & 15;     // t: 16 x 2
    const int ty = tid >> 4;     // r: 16 x 2
    const int rbase = blockIdx.y * 32;
    const int tbase = blockIdx.x * 32;

    const int r0 = 2 * ty, r1 = r0 + 1;
    const int t0 = 2 * tx, t1 = t0 + 1;
    const int sw = ((t0 >> 3) & 3) << 2;      // same for rows t0, t0+1 (t0 even)

    float acc00 = 0.f, acc01 = 0.f, acc10 = 0.f, acc11 = 0.f;

    for (int hc = 0; hc < H_DIM; hc += 256) {
        if (hc) __syncthreads();
        #pragma unroll
        for (int i = 0; i < 8; ++i) {
            int idx = tid + 256 * i;          // 0..2047
            int r = idx >> 6, q = (idx & 63) << 2;
            float4 v = *(const float4*)&rp[(rbase + r) * H_DIM + hc + q];
            *(float4*)&rs[r * SS + q] = v;
            float4 u = *(const float4*)&tp[(tbase + r) * H_DIM + hc + q];
            int s = ((r >> 3) & 3) << 2;
            *(float4*)&ts[r * SS + (q ^ s)] = u;   // bank-spread swizzle
        }
        __syncthreads();

        #pragma unroll 4
        for (int h = 0; h < 256; h += 4) {
            float4 w  = *(const float4*)&W2[hc + h];        // wave-uniform -> s_load
            float4 a0 = *(const float4*)&rs[r0 * SS + h];   // 4 unique addrs/wave (broadcast)
            float4 a1 = *(const float4*)&rs[r1 * SS + h];
            float4 c0 = *(const float4*)&ts[t0 * SS + (h ^ sw)];
            float4 c1 = *(const float4*)&ts[t1 * SS + (h ^ sw)];
            acc00 += w.x*fmaxf(a0.x+c0.x,0.f) + w.y*fmaxf(a0.y+c0.y,0.f)
                   + w.z*fmaxf(a0.z+c0.z,0.f) + w.w*fmaxf(a0.w+c0.w,0.f);
            acc01 += w.x*fmaxf(a0.x+c1.x,0.f) + w.y*fmaxf(a0.y+c1.y,0.f)
                   + w.z*fmaxf(a0.z+c1.z,0.f) + w.w*fmaxf(a0.w+c1.w,0.f);
            acc10 += w.x*fmaxf(a1.x+c0.x,0.f) + w.y*fmaxf(a1.y+c0.y,0.f)
                   + w.z*fmaxf(a1.z+c0.z,0.f) + w.w*fmaxf(a1.w+c0.w,0.f);
            acc11 += w.x*fmaxf(a1.x+c1.x,0.f) + w.y*fmaxf(a1.y+c1.y,0.f)
                   + w.z*fmaxf(a1.z+c1.z,0.f) + w.w*fmaxf(a1.w+c1.w,0.f);
        }
    }

    const float b2v = b2[0];
    const int r = rbase + r0;
    const int t = tbase + t0;
    *(float2*)&out[r * RT + t]       = make_float2(acc00 + b2v, acc01 + b2v);
    *(float2*)&out[(r + 1) * RT + t] = make_float2(acc10 + b2v, acc11 + b2v);
}

extern "C" void kernel_launch(void* const* d_in, const int* in_sizes, int n_in,
                              void* d_out, int out_size, void* d_ws, size_t ws_size,
                              hipStream_t stream) {
    const float* robot = (const float*)d_in[0];
    const float* task  = (const float*)d_in[1];
    const float* W1    = (const float*)d_in[2];
    const float* b1    = (const float*)d_in[3];
    const float* W2    = (const float*)d_in[4];
    const float* b2    = (const float*)d_in[5];
    float* out = (float*)d_out;
    float* ws  = (float*)d_ws;   // 2 MB: rp[512*512] + tp[512*512]

    gemm32<<<dim3(16, 16, 2), dim3(256), 0, stream>>>(robot, task, W1, b1, ws);
    score32<<<dim3(16, 16), dim3(256), 0, stream>>>(ws, W2, b2, out);
}

// Round 3
// 29.892 us; speedup vs baseline: 1.1389x; 1.0396x over previous
//
#include <hip/hip_runtime.h>
#include <hip/hip_bf16.h>

// scores[r,t] = b2 + sum_h W2[h] * relu(rp[r,h] + tp[t,h])
//   rp = robot @ W1[:256] + b1 ; tp = task @ W1[256:]
// Pipeline:
//   prep:  robot/task -> Ab bf16 [z][m][k];  W1 -> Bt bf16 [z][n][k] (transposed)
//   gemm:  MFMA bf16 -> rpT/tpT f32 [h][r]  (transposed, bias folded)
//   score: packed-bf16 LDS, 8 waves split H, in-LDS reduce
// ws layout (floats): rpT[0..262144) | tpT[262144..524288) | Ab (512KB) | Bt (512KB)

#define RT 512
#define DD 256
#define HD 512

typedef __attribute__((ext_vector_type(8))) short bf16x8;
typedef __attribute__((ext_vector_type(4))) float f32x4;

__device__ inline unsigned pkbf(float a, float b) {
    float2 t; t.x = a; t.y = b;
    __hip_bfloat162 h = __float22bfloat162_rn(t);
    return *(unsigned*)&h;
}

// ---------------- prep: convert + transpose ----------------
// blocks 0..63: Bt[z][n][k] = bf16(W1[z*256+k][n])   (64x64 tiles via LDS)
// blocks 64..95: Ab[z][m][k] = bf16(robot/task[m][k])
__global__ __launch_bounds__(256) void prep(
    const float* __restrict__ robot, const float* __restrict__ task,
    const float* __restrict__ W1, unsigned short* __restrict__ Ab,
    unsigned short* __restrict__ Bt)
{
    const int b = blockIdx.x;
    const int tid = threadIdx.x;
    if (b < 64) {
        __shared__ float tile[64 * 68];
        int z = b >> 5, rem = b & 31;
        int nbase = (rem >> 2) * 64, kbase = (rem & 3) * 64;
        int kk = tid >> 4, n4 = (tid & 15) * 4;
        #pragma unroll
        for (int j = 0; j < 4; ++j) {
            int k = kk + 16 * j;
            float4 v = *(const float4*)&W1[(z * DD + kbase + k) * HD + nbase + n4];
            *(float4*)&tile[k * 68 + n4] = v;
        }
        __syncthreads();
        int nn = tid >> 2, kq = (tid & 3) * 16;
        unsigned d[8];
        #pragma unroll
        for (int u = 0; u < 8; ++u)
            d[u] = pkbf(tile[(kq + 2*u) * 68 + nn], tile[(kq + 2*u + 1) * 68 + nn]);
        unsigned* dst = (unsigned*)&Bt[(z * RT + nbase + nn) * DD + kbase + kq];
        *(uint4*)dst       = make_uint4(d[0], d[1], d[2], d[3]);
        *(uint4*)(dst + 4) = make_uint4(d[4], d[5], d[6], d[7]);
    } else {
        int j = b - 64;              // 0..31
        int z = j >> 4, p = j & 15;  // p: 32-row chunk
        const float* src = (z ? task : robot) + p * 8192;
        unsigned short* dst = Ab + z * (RT * DD) + p * 8192;
        #pragma unroll
        for (int u = 0; u < 8; ++u) {
            int idx = tid + 256 * u;            // 0..2047 float4s
            float4 v = *(const float4*)&src[idx * 4];
            *(uint2*)&dst[idx * 4] = make_uint2(pkbf(v.x, v.y), pkbf(v.z, v.w));
        }
    }
}

// ---------------- gemm: C^T via MFMA, writes [h][r] f32 + bias ----------------
// grid (8,8,2): 64m x 64h tile, 4 waves (2x2), K=256 staged once, XOR-swizzled.
__global__ __launch_bounds__(256) void gemm_mfma(
    const unsigned short* __restrict__ Ab, const unsigned short* __restrict__ Bt,
    const float* __restrict__ b1, float* __restrict__ ws)
{
    __shared__ unsigned short As[64 * 256];   // [m][k] bf16, row-XOR-swizzled
    __shared__ unsigned short Bs[64 * 256];   // [n][k] bf16

    const int z = blockIdx.z;
    const int mtile = blockIdx.y * 64;
    const int ntile = blockIdx.x * 64;
    const int tid = threadIdx.x;

    const unsigned short* Asrc = Ab + z * (RT * DD);
    const unsigned short* Bsrc = Bt + z * (RT * DD);

    #pragma unroll
    for (int i = 0; i < 8; ++i) {
        int idx = tid + 256 * i;      // 0..2047 (8-bf16 units)
        int m = idx >> 5, k8 = idx & 31;
        uint4 va = *(const uint4*)&Asrc[(mtile + m) * DD + k8 * 8];
        *(uint4*)((char*)As + ((m * 512 + k8 * 16) ^ ((m & 7) << 4))) = va;
        uint4 vb = *(const uint4*)&Bsrc[(ntile + m) * DD + k8 * 8];
        *(uint4*)((char*)Bs + ((m * 512 + k8 * 16) ^ ((m & 7) << 4))) = vb;
    }
    __syncthreads();

    const int wave = tid >> 6, lane = tid & 63;
    const int wm = (wave >> 1) * 32, wn = (wave & 1) * 32;
    const int lm = lane & 15;
    const int lk = (lane >> 4) * 16;          // byte offset of k-slice

    f32x4 acc[2][2] = {};
    #pragma unroll
    for (int ks = 0; ks < 8; ++ks) {
        bf16x8 a[2], bb[2];
        #pragma unroll
        for (int f = 0; f < 2; ++f) {
            int ra = wm + f * 16 + lm;
            a[f]  = *(const bf16x8*)((const char*)As + ((ra * 512 + ks * 64 + lk) ^ ((ra & 7) << 4)));
            int rb = wn + f * 16 + lm;
            bb[f] = *(const bf16x8*)((const char*)Bs + ((rb * 512 + ks * 64 + lk) ^ ((rb & 7) << 4)));
        }
        #pragma unroll
        for (int i2 = 0; i2 < 2; ++i2)
            #pragma unroll
            for (int j2 = 0; j2 < 2; ++j2)
                acc[i2][j2] = __builtin_amdgcn_mfma_f32_16x16x32_bf16(a[i2], bb[j2], acc[i2][j2], 0, 0, 0);
    }

    float* outT = ws + z * (RT * RT);         // [h][r]
    const int rrow = (lane >> 4) * 4;
    #pragma unroll
    for (int j2 = 0; j2 < 2; ++j2) {
        int h = ntile + wn + j2 * 16 + lm;    // C/D col = lane&15
        float bias = (z == 0) ? b1[h] : 0.f;
        #pragma unroll
        for (int i2 = 0; i2 < 2; ++i2) {
            int r0 = mtile + wm + i2 * 16 + rrow;   // C/D row = (lane>>4)*4 + j
            f32x4 v = acc[i2][j2];
            float4 o; o.x = v[0]+bias; o.y = v[1]+bias; o.z = v[2]+bias; o.w = v[3]+bias;
            *(float4*)&outT[h * RT + r0] = o;
        }
    }
}

// ---------------- score: 32x32 out/block, 8 waves split H, bf16-packed LDS ----------------
__global__ __launch_bounds__(512) void score(
    const float* __restrict__ ws, const float* __restrict__ W2,
    const float* __restrict__ b2, float* __restrict__ out)
{
    __shared__ unsigned smem[16384];          // rs[256][32] | ts[256][32] packed h-pair dwords
    unsigned* rs = smem;
    unsigned* ts = smem + 8192;

    const float* rpT = ws;                    // [h][r]
    const float* tpT = ws + RT * RT;          // [h][t]

    const int tid = threadIdx.x;
    const int rbase = blockIdx.y * 32;
    const int tbase = blockIdx.x * 32;

    #pragma unroll
    for (int i = 0; i < 8; ++i) {
        int idx = tid + 512 * i;              // 0..4095
        int hp = idx >> 4, rq = (idx & 15) * 2;
        float2 v0 = *(const float2*)&rpT[(2*hp)   * RT + rbase + rq];
        float2 v1 = *(const float2*)&rpT[(2*hp+1) * RT + rbase + rq];
        *(uint2*)&rs[hp * 32 + rq] = make_uint2(pkbf(v0.x, v1.x), pkbf(v0.y, v1.y));
        float2 u0 = *(const float2*)&tpT[(2*hp)   * RT + tbase + rq];
        float2 u1 = *(const float2*)&tpT[(2*hp+1) * RT + tbase + rq];
        *(uint2*)&ts[hp * 32 + rq] = make_uint2(pkbf(u0.x, u1.x), pkbf(u0.y, u1.y));
    }
    __syncthreads();

    const int wave = tid >> 6, lane = tid & 63;
    const int ly = lane >> 3, lx = lane & 7;  // 8x8 lanes, micro 4x4
    const int hp0 = wave * 32;                // wave's 64-h chunk

    float accL[4][4] = {}, accH[4][4] = {};
    #pragma unroll 2
    for (int s = 0; s < 32; ++s) {
        int hp = hp0 + s;
        uint4 da = *(const uint4*)&rs[hp * 32 + 4 * ly];   // 8-unique broadcast, conflict-free
        uint4 dc = *(const uint4*)&ts[hp * 32 + 4 * lx];
        float2 w = *(const float2*)&W2[2 * hp];            // wave-uniform -> s_load
        unsigned ua[4] = {da.x, da.y, da.z, da.w};
        unsigned uc[4] = {dc.x, dc.y, dc.z, dc.w};
        float al[4], ah[4], cl[4], ch[4];
        #pragma unroll
        for (int i = 0; i < 4; ++i) {
            al[i] = __uint_as_float(ua[i] << 16);
            ah[i] = __uint_as_float(ua[i] & 0xffff0000u);
            cl[i] = __uint_as_float(uc[i] << 16);
            ch[i] = __uint_as_float(uc[i] & 0xffff0000u);
        }
        #pragma unroll
        for (int i = 0; i < 4; ++i)
            #pragma unroll
            for (int j = 0; j < 4; ++j) {
                accL[i][j] += w.x * fmaxf(al[i] + cl[j], 0.f);
                accH[i][j] += w.y * fmaxf(ah[i] + ch[j], 0.f);
            }
    }

    __syncthreads();                          // all waves done reading rs/ts
    float* red = (float*)smem;                // 8*1024 f32 = 32 KB
    {
        float* p = &red[wave * 1024 + lane * 16];
        #pragma unroll
        for (int i = 0; i < 4; ++i) {
            float4 v;
            v.x = accL[i][0] + accH[i][0];
            v.y = accL[i][1] + accH[i][1];
            v.z = accL[i][2] + accH[i][2];
            v.w = accL[i][3] + accH[i][3];
            *(float4*)&p[4*i] = v;
        }
    }
    __syncthreads();
    const float b2v = b2[0];
    #pragma unroll
    for (int half = 0; half < 2; ++half) {
        int j = tid + half * 512;
        float sum = 0.f;
        #pragma unroll
        for (int w = 0; w < 8; ++w) sum += red[w * 1024 + j];
        int ly2 = j >> 7, lx2 = (j >> 4) & 7, dr = (j >> 2) & 3, dt = j & 3;
        out[(rbase + 4*ly2 + dr) * RT + tbase + 4*lx2 + dt] = sum + b2v;
    }
}

extern "C" void kernel_launch(void* const* d_in, const int* in_sizes, int n_in,
                              void* d_out, int out_size, void* d_ws, size_t ws_size,
                              hipStream_t stream) {
    const float* robot = (const float*)d_in[0];
    const float* task  = (const float*)d_in[1];
    const float* W1    = (const float*)d_in[2];
    const float* b1    = (const float*)d_in[3];
    const float* W2    = (const float*)d_in[4];
    const float* b2    = (const float*)d_in[5];
    float* out = (float*)d_out;
    float* ws  = (float*)d_ws;

    unsigned short* Ab = (unsigned short*)(ws + 2 * RT * RT);   // 512 KB
    unsigned short* Bt = Ab + 2 * RT * DD;                      // 512 KB

    prep<<<96, 256, 0, stream>>>(robot, task, W1, Ab, Bt);
    gemm_mfma<<<dim3(8, 8, 2), 256, 0, stream>>>(Ab, Bt, b1, ws);
    score<<<dim3(16, 16), 512, 0, stream>>>(ws, W2, b2, out);
}

// Round 5
// 19.951 us; speedup vs baseline: 1.7064x; 1.4983x over previous
//
#include <hip/hip_runtime.h>
#include <hip/hip_fp16.h>

// scores[r,t] = b2 + sum_h W2[h] * relu(rp[r,h] + tp[t,h])
//   rp = robot @ W1[:256] + b1 ; tp = task @ W1[256:]
// 2 kernels:
//   K1 gemm_fused: f32->f16 inline, MFMA f16, out rpT/tpT f32 [h][r], bias folded
//   K2 score: LDS h-pair half2, v_pk_add/max_f16 + v_dot2_f32_f16 inner loop
// ws: rpT f32 [512][512] | tpT f32 [512][512]  (2 MB)

#define RT 512
#define DD 256
#define HD 512

typedef _Float16 h2 __attribute__((ext_vector_type(2)));
typedef _Float16 h8 __attribute__((ext_vector_type(8)));
typedef float f32x4 __attribute__((ext_vector_type(4)));

__device__ inline unsigned h2u(h2 v) { return __builtin_bit_cast(unsigned, v); }
__device__ inline h2 u2h(unsigned u) { return __builtin_bit_cast(h2, u); }
__device__ inline h2 pk(float a, float b) {
    return __builtin_bit_cast(h2, __builtin_amdgcn_cvt_pkrtz(a, b));  // v_cvt_pkrtz_f16_f32
}

// ---------------- K1: fused convert + transpose + MFMA GEMM ----------------
// grid (8,16,2): 64 h (n) x 32 r (m) tile, 256 thr (4 waves), K=256 staged once.
__global__ __launch_bounds__(256) void gemm_fused(
    const float* __restrict__ robot, const float* __restrict__ task,
    const float* __restrict__ W1, const float* __restrict__ b1,
    float* __restrict__ ws)
{
    __shared__ __attribute__((aligned(16))) unsigned short As[32 * 256]; // f16 [m][k] swz
    __shared__ __attribute__((aligned(16))) unsigned short Bs[64 * 256]; // f16 [n][k] swz

    const int z = blockIdx.z;
    const int mtile = blockIdx.y * 32;
    const int ntile = blockIdx.x * 64;
    const int tid = threadIdx.x;
    const int wave = tid >> 6, lane = tid & 63;

    const float* A = z ? task : robot;

    // stage A: [32 m][256 k] f32 -> f16, rows 512B, XOR swizzle (m&7)<<4
    #pragma unroll
    for (int it = 0; it < 4; ++it) {
        int idx = tid + 256 * it;          // 0..1023 16B-units
        int m = idx >> 5, k8 = idx & 31;
        const float* src = &A[(mtile + m) * DD + k8 * 8];
        float4 v0 = *(const float4*)src;
        float4 v1 = *(const float4*)(src + 4);
        uint4 o = make_uint4(h2u(pk(v0.x, v0.y)), h2u(pk(v0.z, v0.w)),
                             h2u(pk(v1.x, v1.y)), h2u(pk(v1.z, v1.w)));
        *(uint4*)((char*)As + ((m * 512 + k8 * 16) ^ ((m & 7) << 4))) = o;
    }

    // stage B: W1 [k][n] -> Bs [n=lane][k], strided loads coalesced in n
    {
        const float* Wz = W1 + z * DD * HD;
        #pragma unroll
        for (int k8 = 0; k8 < 8; ++k8) {
            int k0 = wave * 64 + k8 * 8;
            float f[8];
            #pragma unroll
            for (int u = 0; u < 8; ++u)
                f[u] = Wz[(k0 + u) * HD + ntile + lane];
            uint4 o = make_uint4(h2u(pk(f[0], f[1])), h2u(pk(f[2], f[3])),
                                 h2u(pk(f[4], f[5])), h2u(pk(f[6], f[7])));
            *(uint4*)((char*)Bs + ((lane * 512 + k0 * 2) ^ ((lane & 7) << 4))) = o;
        }
    }
    __syncthreads();

    const int wn = wave * 16;          // wave's 16-h strip
    const int lm = lane & 15;
    const int lkb = (lane >> 4) * 16;  // k-slice byte offset

    f32x4 acc0 = {0.f, 0.f, 0.f, 0.f}, acc1 = {0.f, 0.f, 0.f, 0.f};
    #pragma unroll
    for (int ks = 0; ks < 8; ++ks) {
        int rb = wn + lm;
        h8 b  = *(const h8*)((const char*)Bs + ((rb * 512 + ks * 64 + lkb) ^ ((rb & 7) << 4)));
        h8 a0 = *(const h8*)((const char*)As + ((lm * 512 + ks * 64 + lkb) ^ ((lm & 7) << 4)));
        h8 a1 = *(const h8*)((const char*)As + (((16 + lm) * 512 + ks * 64 + lkb) ^ ((lm & 7) << 4)));
        acc0 = __builtin_amdgcn_mfma_f32_16x16x32_f16(a0, b, acc0, 0, 0, 0);
        acc1 = __builtin_amdgcn_mfma_f32_16x16x32_f16(a1, b, acc1, 0, 0, 0);
    }

    // epilogue: D col = lane&15 -> h; rows = (lane>>4)*4+j -> r (verified mapping)
    float* outT = ws + z * (RT * RT);
    const int h = ntile + wn + lm;
    const float bias = (z == 0) ? b1[h] : 0.f;
    const int rrow = (lane >> 4) * 4;
    *(float4*)&outT[h * RT + mtile + rrow] =
        make_float4(acc0[0] + bias, acc0[1] + bias, acc0[2] + bias, acc0[3] + bias);
    *(float4*)&outT[h * RT + mtile + 16 + rrow] =
        make_float4(acc1[0] + bias, acc1[1] + bias, acc1[2] + bias, acc1[3] + bias);
}

// ---------------- K2: score, packed-f16 inner loop ----------------
// grid (16,16), 512 thr (8 waves), 32x32 out tile, waves split 256 h-pairs.
__global__ __launch_bounds__(512) void score(
    const float* __restrict__ ws, const float* __restrict__ W2,
    const float* __restrict__ b2, float* __restrict__ out)
{
    __shared__ __attribute__((aligned(16))) unsigned smem[16384];  // 64 KB
    unsigned* rs = smem;           // [256 hp][32 r] half2-dwords
    unsigned* ts = smem + 8192;    // [256 hp][32 t]

    const float* rpT = ws;
    const float* tpT = ws + RT * RT;
    const int tid = threadIdx.x;
    const int rbase = blockIdx.y * 32, tbase = blockIdx.x * 32;

    #pragma unroll
    for (int i = 0; i < 8; ++i) {
        int u = tid + 512 * i;             // 0..4095 uint4-units (2048 rs, 2048 ts)
        int hp = (u >> 3) & 255;
        int rq = (u & 7) * 4;
        if (u < 2048) {
            float4 v0 = *(const float4*)&rpT[(2 * hp) * RT + rbase + rq];
            float4 v1 = *(const float4*)&rpT[(2 * hp + 1) * RT + rbase + rq];
            *(uint4*)&rs[hp * 32 + rq] = make_uint4(
                h2u(pk(v0.x, v1.x)), h2u(pk(v0.y, v1.y)),
                h2u(pk(v0.z, v1.z)), h2u(pk(v0.w, v1.w)));
        } else {
            float4 v0 = *(const float4*)&tpT[(2 * hp) * RT + tbase + rq];
            float4 v1 = *(const float4*)&tpT[(2 * hp + 1) * RT + tbase + rq];
            *(uint4*)&ts[hp * 32 + rq] = make_uint4(
                h2u(pk(v0.x, v1.x)), h2u(pk(v0.y, v1.y)),
                h2u(pk(v0.z, v1.z)), h2u(pk(v0.w, v1.w)));
        }
    }
    __syncthreads();

    const int wave = tid >> 6, lane = tid & 63;
    const int ly = (lane >> 3) & 7, lx = lane & 7;  // 8x8 lanes, 4x4 micro
    const h2 hzero = {};

    float acc[4][4] = {};
    const int s0 = wave * 32;
    #pragma unroll 4
    for (int s = s0; s < s0 + 32; ++s) {
        uint4 da = *(const uint4*)&rs[s * 32 + 4 * ly];   // broadcast, conflict-free
        uint4 dc = *(const uint4*)&ts[s * 32 + 4 * lx];
        float2 wf = *(const float2*)&W2[2 * s];           // uniform -> s_load
        h2 wv = pk(wf.x, wf.y);
        h2 a[4] = {u2h(da.x), u2h(da.y), u2h(da.z), u2h(da.w)};
        h2 c[4] = {u2h(dc.x), u2h(dc.y), u2h(dc.z), u2h(dc.w)};
        #pragma unroll
        for (int i2 = 0; i2 < 4; ++i2)
            #pragma unroll
            for (int j2 = 0; j2 < 4; ++j2) {
                h2 p = a[i2] + c[j2];                          // v_pk_add_f16
                p = __builtin_elementwise_max(p, hzero);       // v_pk_max_f16
                acc[i2][j2] = __builtin_amdgcn_fdot2(p, wv, acc[i2][j2], false); // v_dot2
            }
    }

    // cross-wave reduce: stride 20 dwords keeps b128 writes bank-balanced
    __syncthreads();
    float* red = (float*)smem;    // 8 * 1280 f32 = 40 KB <= 64 KB
    {
        float* p = &red[wave * 1280 + lane * 20];
        #pragma unroll
        for (int i2 = 0; i2 < 4; ++i2)
            *(float4*)&p[4 * i2] = make_float4(acc[i2][0], acc[i2][1], acc[i2][2], acc[i2][3]);
    }
    __syncthreads();
    const float b2v = b2[0];
    #pragma unroll
    for (int half = 0; half < 2; ++half) {
        int j = tid + half * 512;            // 0..1023 output elements
        float sum = 0.f;
        #pragma unroll
        for (int w = 0; w < 8; ++w) sum += red[w * 1280 + (j >> 4) * 20 + (j & 15)];
        int ly2 = j >> 7, lx2 = (j >> 4) & 7, dr = (j >> 2) & 3, dt = j & 3;
        out[(rbase + 4 * ly2 + dr) * RT + tbase + 4 * lx2 + dt] = sum + b2v;
    }
}

extern "C" void kernel_launch(void* const* d_in, const int* in_sizes, int n_in,
                              void* d_out, int out_size, void* d_ws, size_t ws_size,
                              hipStream_t stream) {
    const float* robot = (const float*)d_in[0];
    const float* task  = (const float*)d_in[1];
    const float* W1    = (const float*)d_in[2];
    const float* b1    = (const float*)d_in[3];
    const float* W2    = (const float*)d_in[4];
    const float* b2    = (const float*)d_in[5];
    float* out = (float*)d_out;
    float* ws  = (float*)d_ws;   // 2 MB

    gemm_fused<<<dim3(8, 16, 2), 256, 0, stream>>>(robot, task, W1, b1, ws);
    score<<<dim3(16, 16), 512, 0, stream>>>(ws, W2, b2, out);
}

// Round 7
// 18.943 us; speedup vs baseline: 1.7971x; 1.0532x over previous
//
#include <hip/hip_runtime.h>
#include <hip/hip_fp16.h>

// scores[r,t] = b2 + sum_h W2[h] * relu(rp[r,h] + tp[t,h])
//   rp = robot @ W1[:256] + b1 ; tp = task @ W1[256:]
// K1 gemm_packed: MFMA f16 (A=W1^T: M=h, B=robot/task: N=r) -> ws packed half2
//                 h-pairs rpP/tpP [256 hp][512 r], bias folded, pk in-lane.
// K2 score:       pure-copy staging, v_pk_add/max_f16 + v_dot2_f32_f16, LDS reduce.
// ws: rpP uint[256*512] | tpP uint[256*512]  (1 MB)
// NOTE: cooperative launch / grid.sync deadlocked the container (R6) — banned here.

#define RT 512
#define DD 256
#define HD 512

typedef _Float16 h2 __attribute__((ext_vector_type(2)));
typedef _Float16 h8 __attribute__((ext_vector_type(8)));
typedef float f32x4 __attribute__((ext_vector_type(4)));

__device__ inline unsigned h2u(h2 v) { return __builtin_bit_cast(unsigned, v); }
__device__ inline h2 u2h(unsigned u) { return __builtin_bit_cast(h2, u); }
__device__ inline h2 pk(float a, float b) {
    return __builtin_bit_cast(h2, __builtin_amdgcn_cvt_pkrtz(a, b));  // v_cvt_pkrtz_f16_f32
}

// ---------------- K1: GEMM -> packed half2 ws ----------------
// 256 blocks x 512 thr. Block b: z=b>>7, rtile=(b&15)*32, htile=((b>>4)&7)*64.
__global__ __launch_bounds__(512) void gemm_packed(
    const float* __restrict__ robot, const float* __restrict__ task,
    const float* __restrict__ W1, const float* __restrict__ b1,
    unsigned* __restrict__ wsu)
{
    __shared__ __attribute__((aligned(16))) unsigned smem[12288];   // 48 KB
    unsigned short* Ws = (unsigned short*)smem;           // f16 [64 h][256 k], swz
    unsigned short* Xs = (unsigned short*)(smem + 8192);  // f16 [32 r][256 k], swz

    const int tid = threadIdx.x;
    const int wave = tid >> 6, lane = tid & 63;
    const int b = blockIdx.x;
    const int z = b >> 7, sub = b & 127;
    const int rtile = (sub & 15) * 32;
    const int htile = (sub >> 4) * 64;
    const float* X = z ? task : robot;
    const float* Wz = W1 + z * DD * HD;

    // stage Ws: W1[k][h] -> Ws[h][k] (lane-coalesced in h), f32->f16
    {
        int hh = tid & 63, k0 = (tid >> 6) * 32;
        float f[32];
        #pragma unroll
        for (int u = 0; u < 32; ++u)
            f[u] = Wz[(k0 + u) * HD + htile + hh];
        #pragma unroll
        for (int j = 0; j < 4; ++j) {
            uint4 o = make_uint4(
                h2u(pk(f[8*j+0], f[8*j+1])), h2u(pk(f[8*j+2], f[8*j+3])),
                h2u(pk(f[8*j+4], f[8*j+5])), h2u(pk(f[8*j+6], f[8*j+7])));
            *(uint4*)((char*)Ws + ((hh * 512 + k0 * 2 + j * 16) ^ ((hh & 7) << 4))) = o;
        }
    }
    // stage Xs: robot/task rows, f32->f16
    #pragma unroll
    for (int i = 0; i < 2; ++i) {
        int idx = tid + 512 * i;          // 0..1023 16B-units
        int m = idx >> 5, k8 = idx & 31;
        const float* src = &X[(rtile + m) * DD + k8 * 8];
        float4 v0 = *(const float4*)src, v1 = *(const float4*)(src + 4);
        uint4 o = make_uint4(h2u(pk(v0.x, v0.y)), h2u(pk(v0.z, v0.w)),
                             h2u(pk(v1.x, v1.y)), h2u(pk(v1.z, v1.w)));
        *(uint4*)((char*)Xs + ((m * 512 + k8 * 16) ^ ((m & 7) << 4))) = o;
    }
    __syncthreads();

    const int wh = (wave & 3) * 16, wr = (wave >> 2) * 16;
    const int lm = lane & 15, lkb = (lane >> 4) * 16;
    f32x4 acc = {0.f, 0.f, 0.f, 0.f};
    #pragma unroll
    for (int ks = 0; ks < 8; ++ks) {
        int ha = wh + lm, ra = wr + lm;
        h8 a  = *(const h8*)((const char*)Ws + ((ha * 512 + ks * 64 + lkb) ^ ((ha & 7) << 4)));
        h8 bb = *(const h8*)((const char*)Xs + ((ra * 512 + ks * 64 + lkb) ^ ((ra & 7) << 4)));
        acc = __builtin_amdgcn_mfma_f32_16x16x32_f16(a, bb, acc, 0, 0, 0);
    }
    // D: col(lane&15) = r, rows (lane>>4)*4+j = h (4 consecutive h per lane)
    const int r  = rtile + wr + lm;
    const int hq = htile + wh + (lane >> 4) * 4;
    float4 bv = make_float4(0.f, 0.f, 0.f, 0.f);
    if (z == 0) bv = *(const float4*)&b1[hq];
    unsigned* P = wsu + z * (256 * RT);
    P[((hq >> 1) + 0) * RT + r] = h2u(pk(acc[0] + bv.x, acc[1] + bv.y));
    P[((hq >> 1) + 1) * RT + r] = h2u(pk(acc[2] + bv.z, acc[3] + bv.w));
}

// ---------------- K2: score ----------------
// grid (16,16), 512 thr (8 waves), 32x32 out tile, waves split 256 h-pairs.
__global__ __launch_bounds__(512) void score(
    const unsigned* __restrict__ wsu, const float* __restrict__ W2,
    const float* __restrict__ b2, float* __restrict__ out)
{
    __shared__ __attribute__((aligned(16))) unsigned smem[16384];  // 64 KB
    unsigned* rs = smem;            // [256 hp][32 r]
    unsigned* ts = smem + 8192;     // [256 hp][32 t]

    const unsigned* rpP = wsu;
    const unsigned* tpP = wsu + 256 * RT;
    const int tid = threadIdx.x;
    const int rbase = blockIdx.y * 32, tbase = blockIdx.x * 32;

    #pragma unroll
    for (int i = 0; i < 8; ++i) {
        int u = tid + 512 * i;              // 0..4095 uint4-units
        int hp = (u >> 3) & 255, rq = (u & 7) * 4;
        if (u < 2048)
            *(uint4*)&rs[hp * 32 + rq] = *(const uint4*)&rpP[hp * RT + rbase + rq];
        else
            *(uint4*)&ts[hp * 32 + rq] = *(const uint4*)&tpP[hp * RT + tbase + rq];
    }
    __syncthreads();

    const int wave = tid >> 6, lane = tid & 63;
    const int ly = (lane >> 3) & 7, lx = lane & 7;   // 8x8 lanes, 4x4 micro
    const h2 hzero = {};
    float acc[4][4] = {};
    const int s0 = wave * 32;
    #pragma unroll 4
    for (int s = s0; s < s0 + 32; ++s) {
        uint4 da = *(const uint4*)&rs[s * 32 + 4 * ly];   // broadcast, conflict-free
        uint4 dc = *(const uint4*)&ts[s * 32 + 4 * lx];
        float2 wf = *(const float2*)&W2[2 * s];           // uniform -> s_load
        h2 wv = pk(wf.x, wf.y);
        h2 a[4] = {u2h(da.x), u2h(da.y), u2h(da.z), u2h(da.w)};
        h2 c[4] = {u2h(dc.x), u2h(dc.y), u2h(dc.z), u2h(dc.w)};
        #pragma unroll
        for (int i2 = 0; i2 < 4; ++i2)
            #pragma unroll
            for (int j2 = 0; j2 < 4; ++j2) {
                h2 p = a[i2] + c[j2];                          // v_pk_add_f16
                p = __builtin_elementwise_max(p, hzero);       // v_pk_max_f16
                acc[i2][j2] = __builtin_amdgcn_fdot2(p, wv, acc[i2][j2], false);
            }
    }

    __syncthreads();                       // all waves done reading rs/ts
    float* red = (float*)smem;             // 8 * 1280 f32 = 40 KB
    {
        float* p = &red[wave * 1280 + lane * 20];
        #pragma unroll
        for (int i2 = 0; i2 < 4; ++i2)
            *(float4*)&p[4 * i2] = make_float4(acc[i2][0], acc[i2][1], acc[i2][2], acc[i2][3]);
    }
    __syncthreads();
    const float b2v = b2[0];
    #pragma unroll
    for (int half = 0; half < 2; ++half) {
        int j = tid + half * 512;          // 0..1023 output elements
        float sum = 0.f;
        #pragma unroll
        for (int w = 0; w < 8; ++w) sum += red[w * 1280 + (j >> 4) * 20 + (j & 15)];
        int ly2 = j >> 7, lx2 = (j >> 4) & 7, dr = (j >> 2) & 3, dt = j & 3;
        out[(rbase + 4 * ly2 + dr) * RT + tbase + 4 * lx2 + dt] = sum + b2v;
    }
}

extern "C" void kernel_launch(void* const* d_in, const int* in_sizes, int n_in,
                              void* d_out, int out_size, void* d_ws, size_t ws_size,
                              hipStream_t stream) {
    const float* robot = (const float*)d_in[0];
    const float* task  = (const float*)d_in[1];
    const float* W1    = (const float*)d_in[2];
    const float* b1    = (const float*)d_in[3];
    const float* W2    = (const float*)d_in[4];
    const float* b2    = (const float*)d_in[5];
    float* out = (float*)d_out;
    unsigned* wsu = (unsigned*)d_ws;   // 1 MB packed rp/tp

    gemm_packed<<<dim3(256), 512, 0, stream>>>(robot, task, W1, b1, wsu);
    score<<<dim3(16, 16), 512, 0, stream>>>(wsu, W2, b2, out);
}